// Round 7
// baseline (657.136 us; speedup 1.0000x reference)
//
#include <hip/hip_runtime.h>
#include <cstdint>

typedef unsigned short u16;
typedef __attribute__((ext_vector_type(8))) __bf16 bf16x8;
typedef __attribute__((ext_vector_type(4))) float f32x4;

#define M_DIM 8192
#define N_DIM 4096
#define K_DIM 4096

#define CVT_W_BLOCKS 2048    // (K/64)*(N/128) register-tile transpose blocks

// round-to-nearest-even f32 -> bf16 (inputs are Gaussian; no NaN handling needed)
__device__ __forceinline__ uint32_t f2bf(float f) {
    union { float f; uint32_t u; } v; v.f = f;
    uint32_t u = v.u;
    u += 0x7FFFu + ((u >> 16) & 1u);
    return u >> 16;
}

// ---------------- w converter: f32 (K,N) -> bf16^T (N,K), register transpose ----
// lane reads 8 k-rows x 4 n (float4), repacks in-reg, writes 4 n-rows x 8 k
// (uint4, 8 lanes form 128B segments). No LDS, no barrier. x-conversion is GONE:
// fused into the GEMM A-path (this round's experiment).
__global__ __launch_bounds__(256) void cvt_kernel(const float* __restrict__ w,
                                                  u16* __restrict__ wt) {
    const int t = threadIdx.x;
    const int bid = blockIdx.x;                  // 0..2047
    const int k0 = (bid & 63) * 64;              // 64 k-tiles
    const int n0 = (bid >> 6) * 128;             // 32 n-tiles
    const int wv = t >> 6, l = t & 63;
    const int a  = l & 7;                        // k-block of 8 within wave
    const int g  = l >> 3;                       // n-group of 4 within wave
    const int kk = k0 + a * 8;
    const int nn = n0 + wv * 32 + g * 4;

    uint32_t b[8][4];                            // b[j][i]: k=kk+j, n=nn+i
#pragma unroll
    for (int j = 0; j < 8; ++j) {
        float4 v = *(const float4*)&w[(size_t)(kk + j) * N_DIM + nn];
        b[j][0] = f2bf(v.x); b[j][1] = f2bf(v.y);
        b[j][2] = f2bf(v.z); b[j][3] = f2bf(v.w);
    }
#pragma unroll
    for (int i = 0; i < 4; ++i) {
        uint4 o;
        o.x = b[0][i] | (b[1][i] << 16);
        o.y = b[2][i] | (b[3][i] << 16);
        o.z = b[4][i] | (b[5][i] << 16);
        o.w = b[6][i] | (b[7][i] << 16);
        *(uint4*)&wt[(size_t)(nn + i) * K_DIM + kk] = o;
    }
}

// ---------------- GEMM: C = bf16(X)(M,K) @ Bt(N,K)^T + bias ----------------
// 256x256 tile, BK=32, 8 waves (2M x 4N, 128x64/wave), double-buffered LDS.
// A-path FUSED f32->bf16 (this round): issue 4 f32 global loads for tile t+1
// early; after the MFMA cluster, compiler-inserted vmcnt proves them; convert
// + 2 ds_write_b128 into the swizzled slot of As[pb]. X is read exactly once,
// hidden under MFMA. B-path unchanged (gload_lds, pre-swizzled global source).
// As stride = 40 u16 (80 B): 16B-aligned slots, rotates banks across rows so
// the 4-lane-per-row b128 writes/reads spread ~evenly (vs 8-way at stride 32).
//
// Wait ledger (per thread per iter, in-order issue: A-f32 x4 then B-lds x2):
//   entry iter t: outstanding = [B(t) x2]
//   issue A(t+1) x4, B(t+1) x2 -> 8; vmcnt(6) drains B(t) -> safe to read Bs[nb]
//   after MFMA: compiler auto-wait (vmcnt(2)) proves A(t+1) regs; cvt+ds_write
//   -> entry iter t+1: [B(t+1) x2]. Never drains to 0.
// Cross-wave visibility: lgkmcnt(0) immediately before the phase barrier makes
// each wave's prev-iter As-writes visible before any wave reads them.
// WAR: As[pb] last read in iter t-1 (>=1 barrier before this iter's write);
// Bs[pb] last read in iter t-1, end-of-iter barrier separates.
typedef const uint32_t __attribute__((address_space(1)))* gp_t;
typedef uint32_t __attribute__((address_space(3)))* lp_t;

#define BK 32
#define NTILES (K_DIM / BK)            // 128
#define TN_TILES (N_DIM / 256)         // 16
#define NWG ((M_DIM / 256) * TN_TILES) // 512

__global__ __launch_bounds__(512, 2) void gemm_kernel(const float* __restrict__ X,
                                                      const u16* __restrict__ Bt,
                                                      const float* __restrict__ bias,
                                                      float* __restrict__ C) {
    __shared__ u16 As[2][256][40];   // 40 KB, ds_write path (stride 80 B)
    __shared__ u16 Bs[2][256][32];   // 32 KB, gload_lds path (stride 64 B)

    const int t    = threadIdx.x;
    const int lane = t & 63;
    const int l16  = lane & 15;
    const int quad = lane >> 4;
    const int wave = t >> 6;       // 0..7
    const int wr   = wave >> 2;    // 0..1 (M): rows wr*128..+128
    const int wc   = wave & 3;     // 0..3 (N): cols wc*64..+64

    // XCD-aware bijective swizzle (NWG % 8 == 0): same-XCD blocks share A-panel
    const int bid = blockIdx.x;
    const int wg  = (bid & 7) * (NWG >> 3) + (bid >> 3);
    const int bm  = (wg / TN_TILES) * 256;
    const int bn  = (wg % TN_TILES) * 256;

    // staging geometry: thread owns 16B chunks {t, t+512}; row = c>>2, chunk = c&3.
    const int rC0  = t >> 2;
    const int rC1  = rC0 + 128;
    const int qs   = t & 3;                          // logical chunk (natural order)
    const int slot = qs ^ ((rC0 >> 1) & 3);          // XOR-swizzled LDS slot (same for rC1)
    // A: read natural chunk from f32 X, ds_write to swizzled slot.
    const float* xa0 = X + (size_t)(bm + rC0) * K_DIM + qs * 8;
    const float* xa1 = X + (size_t)(bm + rC1) * K_DIM + qs * 8;
    // B: gload_lds linear dest, pre-swizzled global k-chunk (R0-proven, 0 conflicts).
    const int kcS = slot * 8;
    const u16* b0 = Bt + (size_t)(bn + rC0) * K_DIM + kcS;
    const u16* b1 = Bt + (size_t)(bn + rC1) * K_DIM + kcS;

    // read-side swizzled slot offset (uniform over i/j: row bases are mult of 16)
    const int sw8 = (quad ^ ((l16 >> 1) & 3)) * 8;

    f32x4 acc[8][4] = {};
    bf16x8 af[8], bf[4];

#define STAGE_B(buf, kk) do {                                                                   \
        __builtin_amdgcn_global_load_lds((gp_t)(b0 + (kk)), (lp_t)&Bs[buf][rC0][qs * 8], 16, 0, 0); \
        __builtin_amdgcn_global_load_lds((gp_t)(b1 + (kk)), (lp_t)&Bs[buf][rC1][qs * 8], 16, 0, 0); \
    } while (0)
#define CVT_WRITE_A(buf)  do {                                                \
        uint4 o0, o1;                                                         \
        o0.x = f2bf(a00.x) | (f2bf(a00.y) << 16);                             \
        o0.y = f2bf(a00.z) | (f2bf(a00.w) << 16);                             \
        o0.z = f2bf(a01.x) | (f2bf(a01.y) << 16);                             \
        o0.w = f2bf(a01.z) | (f2bf(a01.w) << 16);                             \
        o1.x = f2bf(a10.x) | (f2bf(a10.y) << 16);                             \
        o1.y = f2bf(a10.z) | (f2bf(a10.w) << 16);                             \
        o1.z = f2bf(a11.x) | (f2bf(a11.y) << 16);                             \
        o1.w = f2bf(a11.z) | (f2bf(a11.w) << 16);                             \
        *(uint4*)&As[buf][rC0][slot * 8] = o0;                                \
        *(uint4*)&As[buf][rC1][slot * 8] = o1;                                \
    } while (0)

    // prologue: A(0) f32 -> cvt -> As[0] (compiler auto-waits the loads);
    // B(0) gload_lds in flight (2 outstanding entering the loop).
    float4 a00 = *(const float4*)(xa0 + 0), a01 = *(const float4*)(xa0 + 4);
    float4 a10 = *(const float4*)(xa1 + 0), a11 = *(const float4*)(xa1 + 4);
    STAGE_B(0, 0);
    CVT_WRITE_A(0);

#pragma unroll 2
    for (int tt = 0; tt < NTILES; ++tt) {
        const int nb = tt & 1;
        const int pb = nb ^ 1;
        const int kn = (tt + 1 < NTILES) ? (tt + 1) * BK : 0;  // clamped dummy tail

        // issue tile t+1: A f32 to regs, B to LDS  (outstanding -> 8)
        a00 = *(const float4*)(xa0 + kn); a01 = *(const float4*)(xa0 + kn + 4);
        a10 = *(const float4*)(xa1 + kn); a11 = *(const float4*)(xa1 + kn + 4);
        STAGE_B(pb, kn);

        asm volatile("s_waitcnt vmcnt(6)" ::: "memory");   // tile t's B landed
        asm volatile("s_waitcnt lgkmcnt(0)" ::: "memory"); // my As[nb] writes published
        __builtin_amdgcn_s_barrier();                      // ...for all waves

#pragma unroll
        for (int i = 0; i < 8; ++i)
            af[i] = *(const bf16x8*)&As[nb][wr * 128 + i * 16 + l16][sw8];
#pragma unroll
        for (int j = 0; j < 4; ++j)
            bf[j] = *(const bf16x8*)&Bs[nb][wc * 64 + j * 16 + l16][sw8];

        __builtin_amdgcn_s_setprio(1);
#pragma unroll
        for (int i = 0; i < 8; ++i)
#pragma unroll
            for (int j = 0; j < 4; ++j)
                acc[i][j] = __builtin_amdgcn_mfma_f32_16x16x32_bf16(af[i], bf[j], acc[i][j], 0, 0, 0);
        __builtin_amdgcn_s_setprio(0);

        // convert tile t+1's A (compiler inserts precise vmcnt for the f32 regs;
        // B(t+1) gload_lds stay in flight) and write into As[pb].
        CVT_WRITE_A(pb);

        __builtin_amdgcn_s_barrier();   // Bs[nb] reads done -> next iter may overwrite
    }

    // epilogue: C/D layout col=lane&15, row=quad*4+r (m89/m91-verified); fuse bias
#pragma unroll
    for (int j = 0; j < 4; ++j) {
        const int col = bn + wc * 64 + j * 16 + l16;
        const float bv = bias[col];
#pragma unroll
        for (int i = 0; i < 8; ++i) {
            const int row = bm + wr * 128 + i * 16 + quad * 4;
#pragma unroll
            for (int r = 0; r < 4; ++r)
                C[(size_t)(row + r) * N_DIM + col] = acc[i][j][r] + bv;
        }
    }
#undef STAGE_B
#undef CVT_WRITE_A
}

extern "C" void kernel_launch(void* const* d_in, const int* in_sizes, int n_in,
                              void* d_out, int out_size, void* d_ws, size_t ws_size,
                              hipStream_t stream) {
    const float* x = (const float*)d_in[0];   // (8192, 4096) f32
    const float* w = (const float*)d_in[1];   // (4096, 4096) f32
    const float* b = (const float*)d_in[2];   // (4096,)      f32
    float* out = (float*)d_out;               // (8192, 4096) f32

    // workspace: wt (N*K bf16, 32MB) only — xb is gone (A-cvt fused into gemm)
    u16* wt = (u16*)d_ws;

    cvt_kernel<<<CVT_W_BLOCKS, 256, 0, stream>>>(w, wt);
    gemm_kernel<<<dim3(NWG), 512, 0, stream>>>(x, wt, b, out);
}

// Round 8
// 611.526 us; speedup vs baseline: 1.0746x; 1.0746x over previous
//
#include <hip/hip_runtime.h>
#include <cstdint>

typedef unsigned short u16;
typedef __attribute__((ext_vector_type(8))) __bf16 bf16x8;
typedef __attribute__((ext_vector_type(4))) float f32x4;

#define M_DIM 8192
#define N_DIM 4096
#define K_DIM 4096

#define CVT_X_BLOCKS 16384   // (M*K)/(256*8)
#define CVT_W_BLOCKS 2048    // (K/64)*(N/128) register-tile transpose blocks

// round-to-nearest-even f32 -> bf16 (inputs are Gaussian; no NaN handling needed)
__device__ __forceinline__ uint32_t f2bf(float f) {
    union { float f; uint32_t u; } v; v.f = f;
    uint32_t u = v.u;
    u += 0x7FFFu + ((u >> 16) & 1u);
    return u >> 16;
}

// ---------------- merged converter: one launch for both inputs ----------------
// blocks [0, CVT_X_BLOCKS): x f32 (M,K) -> bf16 (M,K), streaming
// blocks [CVT_X_BLOCKS, +CVT_W_BLOCKS): w f32 (K,N) -> bf16^T (N,K), register
// transpose (R6-verified). cvt total ~77us vs 56us traffic roofline; the
// remaining ~177us of (total - gemm - cvt) is fixed harness overhead (R7 exp).
__global__ __launch_bounds__(256) void cvt_kernel(const float* __restrict__ x,
                                                  const float* __restrict__ w,
                                                  u16* __restrict__ xb,
                                                  u16* __restrict__ wt) {
    const int t = threadIdx.x;
    if (blockIdx.x < CVT_X_BLOCKS) {
        size_t i = ((size_t)blockIdx.x * 256 + t) * 8;
        const float4* p = (const float4*)(x + i);
        float4 v0 = p[0], v1 = p[1];
        uint4 o;
        o.x = f2bf(v0.x) | (f2bf(v0.y) << 16);
        o.y = f2bf(v0.z) | (f2bf(v0.w) << 16);
        o.z = f2bf(v1.x) | (f2bf(v1.y) << 16);
        o.w = f2bf(v1.z) | (f2bf(v1.w) << 16);
        *(uint4*)(xb + i) = o;
    } else {
        // block tile: 64 k x 128 n. 4 waves stacked in n (32 n each).
        const int bid = blockIdx.x - CVT_X_BLOCKS;   // 0..2047
        const int k0 = (bid & 63) * 64;              // 64 k-tiles
        const int n0 = (bid >> 6) * 128;             // 32 n-tiles
        const int wv = t >> 6, l = t & 63;
        const int a  = l & 7;                        // k-block of 8 within wave
        const int g  = l >> 3;                       // n-group of 4 within wave
        const int kk = k0 + a * 8;
        const int nn = n0 + wv * 32 + g * 4;

        uint32_t b[8][4];                            // b[j][i]: k=kk+j, n=nn+i
#pragma unroll
        for (int j = 0; j < 8; ++j) {
            float4 v = *(const float4*)&w[(size_t)(kk + j) * N_DIM + nn];
            b[j][0] = f2bf(v.x); b[j][1] = f2bf(v.y);
            b[j][2] = f2bf(v.z); b[j][3] = f2bf(v.w);
        }
#pragma unroll
        for (int i = 0; i < 4; ++i) {
            uint4 o;
            o.x = b[0][i] | (b[1][i] << 16);
            o.y = b[2][i] | (b[3][i] << 16);
            o.z = b[4][i] | (b[5][i] << 16);
            o.w = b[6][i] | (b[7][i] << 16);
            *(uint4*)&wt[(size_t)(nn + i) * K_DIM + kk] = o;
        }
    }
}

// ---------------- GEMM: C = A(M,K) @ Bt(N,K)^T + bias ----------------
// 256x256 tile, BK=32, 8 waves (2M x 4N, 128x64/wave), double-buffered LDS.
// R6 shell unchanged (ledger, swizzles, barriers). THIS ROUND's single change:
// break the read-convoy. R6 issued all 12 ds_reads then all 32 MFMAs; with
// af-first source order the first MFMA waited the 12th read -> phases fully
// serial (measured 2812 cyc/iter = 1408 LDS + 1242 MFMA + sync; MfmaUtil 40%).
// Now: bf[0..3] issued FIRST, af[i] trickled 2 groups ahead of its MFMA group.
// Compiler's fine-grained lgkmcnt (m97-verified) then gates per-group: MFMA
// group i starts when its read lands; MFMA issue (~78 cyc/group) paces LDS
// delivery (~96 cyc/group) -> read pipe and matrix pipe overlap.
//
// Wait ledger (2 loads per STAGE call, 4/thread/tile):
//   entry iter t: outstanding = t's 4 (issued last iter / prologue)
//   issue t+1's 4 -> 8; vmcnt(4) -> t's 4 landed; barrier -> all waves proven.
//   WAR: stage into buf[pb] is >=1 barrier after last read of buf[pb] (iter t-1).
typedef const uint32_t __attribute__((address_space(1)))* gp_t;
typedef uint32_t __attribute__((address_space(3)))* lp_t;

#define BK 32
#define NTILES (K_DIM / BK)            // 128
#define TN_TILES (N_DIM / 256)         // 16
#define NWG ((M_DIM / 256) * TN_TILES) // 512

__global__ __launch_bounds__(512, 2) void gemm_kernel(const u16* __restrict__ A,
                                                      const u16* __restrict__ Bt,
                                                      const float* __restrict__ bias,
                                                      float* __restrict__ C) {
    // [buf][row][k32]; 64B row stride; XOR chunk swizzle -> 0 conflicts (measured)
    __shared__ u16 As[2][256][32];   // 32 KB
    __shared__ u16 Bs[2][256][32];   // 32 KB

    const int t    = threadIdx.x;
    const int lane = t & 63;
    const int l16  = lane & 15;
    const int quad = lane >> 4;
    const int wave = t >> 6;       // 0..7
    const int wr   = wave >> 2;    // 0..1 (M): rows wr*128..+128
    const int wc   = wave & 3;     // 0..3 (N): cols wc*64..+64

    // XCD-aware bijective swizzle (NWG % 8 == 0): same-XCD blocks share A-panel
    const int bid = blockIdx.x;
    const int wg  = (bid & 7) * (NWG >> 3) + (bid >> 3);
    const int bm  = (wg / TN_TILES) * 256;
    const int bn  = (wg % TN_TILES) * 256;

    // staging: thread owns 16B chunks {t, t+512}; row = c>>2, slot = c&3.
    // LDS dest linear; global source k-chunk pre-swizzled (slot ^ ((row>>1)&3)).
    const int rC0 = t >> 2;
    const int rC1 = rC0 + 128;
    const int kcS = ((t & 3) ^ ((rC0 >> 1) & 3)) * 8;
    const u16* a0 = A  + (size_t)(bm + rC0) * K_DIM + kcS;
    const u16* a1 = A  + (size_t)(bm + rC1) * K_DIM + kcS;
    const u16* b0 = Bt + (size_t)(bn + rC0) * K_DIM + kcS;
    const u16* b1 = Bt + (size_t)(bn + rC1) * K_DIM + kcS;

    // read-side swizzled slot offset (uniform over i/j: row bases are mult of 16)
    const int sw8 = (quad ^ ((l16 >> 1) & 3)) * 8;

    f32x4 acc[8][4] = {};
    bf16x8 af[8], bf[4];

#define STAGE_A(buf, kk) do {                                                                   \
        __builtin_amdgcn_global_load_lds((gp_t)(a0 + (kk)), (lp_t)&As[buf][rC0][(t & 3) * 8], 16, 0, 0); \
        __builtin_amdgcn_global_load_lds((gp_t)(a1 + (kk)), (lp_t)&As[buf][rC1][(t & 3) * 8], 16, 0, 0); \
    } while (0)
#define STAGE_B(buf, kk) do {                                                                   \
        __builtin_amdgcn_global_load_lds((gp_t)(b0 + (kk)), (lp_t)&Bs[buf][rC0][(t & 3) * 8], 16, 0, 0); \
        __builtin_amdgcn_global_load_lds((gp_t)(b1 + (kk)), (lp_t)&Bs[buf][rC1][(t & 3) * 8], 16, 0, 0); \
    } while (0)

    // prologue: stage tile 0 into buf0 (4 loads outstanding)
    STAGE_A(0, 0); STAGE_B(0, 0);

#pragma unroll 2
    for (int tt = 0; tt < NTILES; ++tt) {
        const int nb = tt & 1;
        const int pb = nb ^ 1;
        const int kn = (tt + 1 < NTILES) ? (tt + 1) * BK : 0;  // clamped dummy tail

        STAGE_A(pb, kn); STAGE_B(pb, kn);                 // outstanding: 8
        asm volatile("s_waitcnt vmcnt(4)" ::: "memory");  // tile tt landed (own wave)
        __builtin_amdgcn_s_barrier();                     // ...and for all waves

        // B fragments first (needed by EVERY group), then prime 2 A-groups
#pragma unroll
        for (int j = 0; j < 4; ++j)
            bf[j] = *(const bf16x8*)&Bs[nb][wc * 64 + j * 16 + l16][sw8];
        af[0] = *(const bf16x8*)&As[nb][wr * 128 + 0 * 16 + l16][sw8];
        af[1] = *(const bf16x8*)&As[nb][wr * 128 + 1 * 16 + l16][sw8];

        // trickle: read af[i+2] two groups ahead of MFMA group i; per-group
        // lgkmcnt gating lets the matrix pipe run while LDS serves the rest
        __builtin_amdgcn_s_setprio(1);
#pragma unroll
        for (int i = 0; i < 8; ++i) {
            if (i < 6)
                af[i + 2] = *(const bf16x8*)&As[nb][wr * 128 + (i + 2) * 16 + l16][sw8];
#pragma unroll
            for (int j = 0; j < 4; ++j)
                acc[i][j] = __builtin_amdgcn_mfma_f32_16x16x32_bf16(af[i], bf[j], acc[i][j], 0, 0, 0);
        }
        __builtin_amdgcn_s_setprio(0);

        __builtin_amdgcn_s_barrier();   // reads of buf[nb] done -> next iter may stage into it
    }

    // epilogue: C/D layout col=lane&15, row=quad*4+r (m89/m91-verified); fuse bias
#pragma unroll
    for (int j = 0; j < 4; ++j) {
        const int col = bn + wc * 64 + j * 16 + l16;
        const float bv = bias[col];
#pragma unroll
        for (int i = 0; i < 8; ++i) {
            const int row = bm + wr * 128 + i * 16 + quad * 4;
#pragma unroll
            for (int r = 0; r < 4; ++r)
                C[(size_t)(row + r) * N_DIM + col] = acc[i][j][r] + bv;
        }
    }
#undef STAGE_A
#undef STAGE_B
}

extern "C" void kernel_launch(void* const* d_in, const int* in_sizes, int n_in,
                              void* d_out, int out_size, void* d_ws, size_t ws_size,
                              hipStream_t stream) {
    const float* x = (const float*)d_in[0];   // (8192, 4096) f32
    const float* w = (const float*)d_in[1];   // (4096, 4096) f32
    const float* b = (const float*)d_in[2];   // (4096,)      f32
    float* out = (float*)d_out;               // (8192, 4096) f32

    // workspace: xb (M*K bf16, 64MB) + wt (N*K bf16, 32MB) = 96MB
    u16* xb = (u16*)d_ws;
    u16* wt = xb + (size_t)M_DIM * K_DIM;

    cvt_kernel<<<CVT_X_BLOCKS + CVT_W_BLOCKS, 256, 0, stream>>>(x, w, xb, wt);
    gemm_kernel<<<dim3(NWG), 512, 0, stream>>>(xb, wt, b, out);
}